// Round 1
// baseline (2207.968 us; speedup 1.0000x reference)
//
#include <hip/hip_runtime.h>
#include <hip/hip_bf16.h>
#include <math.h>

#define N_USERS_C 100000

// ---------------- elementwise helpers ----------------
__global__ void k_set(float* __restrict__ p, float v, int n) {
    int i = blockIdx.x * 256 + threadIdx.x;
    if (i < n) p[i] = v;
}

__global__ void k_count(const int* __restrict__ dst, float* __restrict__ deg, int E) {
    int i = blockIdx.x * 256 + threadIdx.x;
    if (i < E) atomicAdd(&deg[dst[i]], 1.0f);
}

__global__ void k_rsqrt_inplace(float* __restrict__ p, int n) {
    int i = blockIdx.x * 256 + threadIdx.x;
    if (i < n) p[i] = rsqrtf(p[i]);
}

// ---------------- GEMM: Y[N,C] = X[N,K] @ W[K,C] ----------------
template<int K, int C>
__global__ __launch_bounds__(256) void k_gemm(const float* __restrict__ X,
                                              const float* __restrict__ W,
                                              float* __restrict__ Y, int N) {
    constexpr int ROWS = 64;
    __shared__ float sW[K * C];
    __shared__ float sX[ROWS * K];
    const int t = threadIdx.x;
    const int row0 = blockIdx.x * ROWS;

    for (int i = t; i < K * C; i += 256) sW[i] = W[i];
    for (int i = t; i < ROWS * K; i += 256) {
        int r = i / K, k = i - r * K;
        int row = row0 + r;
        sX[i] = (row < N) ? X[(size_t)row * K + k] : 0.0f;
    }
    __syncthreads();

    for (int i = t; i < ROWS * C; i += 256) {
        int r = i / C, c = i - r * C;
        int row = row0 + r;
        if (row < N) {
            float acc = 0.0f;
            #pragma unroll 8
            for (int k = 0; k < K; ++k) acc += sX[r * K + k] * sW[k * C + c];
            Y[(size_t)row * C + c] = acc;
        }
    }
}

// ---------------- edge aggregation: agg[dst] += xw[src] * norm ----------------
template<int C>
__global__ __launch_bounds__(256) void k_agg(const int* __restrict__ src,
                                             const int* __restrict__ dst,
                                             const float* __restrict__ dinv,
                                             const float* __restrict__ xw,
                                             float* __restrict__ agg, int E) {
    constexpr int EPB = 256 / C;      // edges per block
    const int t = threadIdx.x;
    const int e = blockIdx.x * EPB + t / C;
    if (e >= E) return;
    const int f = t & (C - 1);
    const int s = src[e];
    const int d = dst[e];
    const float nrm = dinv[s] * dinv[d];
    atomicAdd(&agg[(size_t)d * C + f], xw[(size_t)s * C + f] * nrm);
}

// ---------------- finish: h = [relu](agg + xw/deg + b), in place on agg ----------------
template<int C, bool RELU>
__global__ void k_finish(float* __restrict__ agg, const float* __restrict__ xw,
                         const float* __restrict__ dinv, const float* __restrict__ bias,
                         int N) {
    int idx = blockIdx.x * 256 + threadIdx.x;
    if (idx >= N * C) return;
    int r = idx / C, c = idx - r * C;
    float di = dinv[r];
    float v = agg[idx] + xw[idx] * di * di + bias[c];
    if (RELU) v = fmaxf(v, 0.0f);
    agg[idx] = v;
}

// ---------------- MLP head: one wave (64 threads) per output row ----------------
__global__ __launch_bounds__(64) void k_mlp(const float* __restrict__ h,
                                            const int* __restrict__ ui,
                                            const int* __restrict__ ii,
                                            const float* __restrict__ fcW1, const float* __restrict__ fcb1,
                                            const float* __restrict__ g1,   const float* __restrict__ be1,
                                            const float* __restrict__ fcW2, const float* __restrict__ fcb2,
                                            const float* __restrict__ g2,   const float* __restrict__ be2,
                                            const float* __restrict__ fcW3, const float* __restrict__ fcb3,
                                            float* __restrict__ out, int nUsers) {
    const int b = blockIdx.x;
    const int lane = threadIdx.x;   // 0..63
    __shared__ float sc[128];
    __shared__ float sz[128];

    const int u  = ui[b] - 1;
    const int it = nUsers + ii[b] - 1;
    sc[lane]      = h[(size_t)u  * 64 + lane];
    sc[lane + 64] = h[(size_t)it * 64 + lane];
    __syncthreads();

    // fc1: 128 -> 128, each lane computes outputs lane and lane+64
    float v0 = fcb1[lane], v1 = fcb1[lane + 64];
    #pragma unroll 4
    for (int k = 0; k < 128; ++k) {
        float ck = sc[k];
        v0 += ck * fcW1[k * 128 + lane];
        v1 += ck * fcW1[k * 128 + lane + 64];
    }
    float s = v0 + v1;
    float ss = v0 * v0 + v1 * v1;
    #pragma unroll
    for (int m = 32; m; m >>= 1) { s += __shfl_xor(s, m); ss += __shfl_xor(ss, m); }
    float mu  = s * (1.0f / 128.0f);
    float var = ss * (1.0f / 128.0f) - mu * mu;
    float rs  = rsqrtf(var + 1e-5f);
    v0 = (v0 - mu) * rs * g1[lane]      + be1[lane];      v0 = fmaxf(v0, 0.0f);
    v1 = (v1 - mu) * rs * g1[lane + 64] + be1[lane + 64]; v1 = fmaxf(v1, 0.0f);
    sz[lane] = v0; sz[lane + 64] = v1;
    __syncthreads();

    // fc2: 128 -> 64, one output per lane
    float w = fcb2[lane];
    #pragma unroll 4
    for (int k = 0; k < 128; ++k) w += sz[k] * fcW2[k * 64 + lane];
    s = w; ss = w * w;
    #pragma unroll
    for (int m = 32; m; m >>= 1) { s += __shfl_xor(s, m); ss += __shfl_xor(ss, m); }
    mu  = s * (1.0f / 64.0f);
    var = ss * (1.0f / 64.0f) - mu * mu;
    rs  = rsqrtf(var + 1e-5f);
    w = (w - mu) * rs * g2[lane] + be2[lane];
    w = fmaxf(w, 0.0f);

    // fc3: 64 -> 1 dot + sigmoid
    float p = w * fcW3[lane];
    #pragma unroll
    for (int m = 32; m; m >>= 1) p += __shfl_xor(p, m);
    if (lane == 0) out[b] = 1.0f / (1.0f + expf(-(p + fcb3[0])));
}

extern "C" void kernel_launch(void* const* d_in, const int* in_sizes, int n_in,
                              void* d_out, int out_size, void* d_ws, size_t ws_size,
                              hipStream_t stream) {
    const float* x    = (const float*)d_in[0];
    const int*   src  = (const int*)d_in[1];
    const int*   dst  = (const int*)d_in[2];
    const int*   ui   = (const int*)d_in[3];
    const int*   ii   = (const int*)d_in[4];
    const float* W1   = (const float*)d_in[5];
    const float* b1   = (const float*)d_in[6];
    const float* W2   = (const float*)d_in[7];
    const float* b2   = (const float*)d_in[8];
    const float* fcW1 = (const float*)d_in[9];
    const float* fcb1 = (const float*)d_in[10];
    const float* g1   = (const float*)d_in[11];
    const float* be1  = (const float*)d_in[12];
    const float* fcW2 = (const float*)d_in[13];
    const float* fcb2 = (const float*)d_in[14];
    const float* g2   = (const float*)d_in[15];
    const float* be2  = (const float*)d_in[16];
    const float* fcW3 = (const float*)d_in[17];
    const float* fcb3 = (const float*)d_in[18];
    float* out = (float*)d_out;

    const int N = in_sizes[0] / 64;   // 150000
    const int E = in_sizes[1];        // 2400000
    const int B = in_sizes[3];        // 16384

    float* ws   = (float*)d_ws;
    float* dinv = ws;                          // N
    float* bufA = ws + N;                      // N*128 (xw1, then xw2)
    float* bufB = bufA + (size_t)N * 128;      // N*128 (agg1/h1, then agg2/h2)

    // degree -> dinv
    k_set<<<(N + 255) / 256, 256, 0, stream>>>(dinv, 1.0f, N);
    k_count<<<(E + 255) / 256, 256, 0, stream>>>(dst, dinv, E);
    k_rsqrt_inplace<<<(N + 255) / 256, 256, 0, stream>>>(dinv, N);

    // layer 1: xw1 = x @ W1 (K=64, C=128)
    k_gemm<64, 128><<<(N + 63) / 64, 256, 0, stream>>>(x, W1, bufA, N);
    k_set<<<((N * 128) + 255) / 256, 256, 0, stream>>>(bufB, 0.0f, N * 128);
    k_agg<128><<<(E + 1) / 2, 256, 0, stream>>>(src, dst, dinv, bufA, bufB, E);
    k_finish<128, true><<<((N * 128) + 255) / 256, 256, 0, stream>>>(bufB, bufA, dinv, b1, N);

    // layer 2: xw2 = h1 @ W2 (K=128, C=64)
    k_gemm<128, 64><<<(N + 63) / 64, 256, 0, stream>>>(bufB, W2, bufA, N);
    k_set<<<((N * 64) + 255) / 256, 256, 0, stream>>>(bufB, 0.0f, N * 64);
    k_agg<64><<<(E + 3) / 4, 256, 0, stream>>>(src, dst, dinv, bufA, bufB, E);
    k_finish<64, false><<<((N * 64) + 255) / 256, 256, 0, stream>>>(bufB, bufA, dinv, b2, N);

    // MLP head
    k_mlp<<<B, 64, 0, stream>>>(bufB, ui, ii,
                                fcW1, fcb1, g1, be1,
                                fcW2, fcb2, g2, be2,
                                fcW3, fcb3, out, N_USERS_C);
}

// Round 2
// 1092.235 us; speedup vs baseline: 2.0215x; 2.0215x over previous
//
#include <hip/hip_runtime.h>
#include <hip/hip_bf16.h>
#include <math.h>

#define N_USERS_C 100000

// ---------------- small helpers ----------------
__global__ void k_zero_i(int* __restrict__ p, int n) {
    int i = blockIdx.x * 256 + threadIdx.x;
    if (i < n) p[i] = 0;
}

__global__ void k_hist(const int* __restrict__ dst, int* __restrict__ cnt, int E) {
    int i = blockIdx.x * 256 + threadIdx.x;
    if (i < E) atomicAdd(&cnt[dst[i]], 1);
}

// ---------------- two-level exclusive scan over cnt[N] ----------------
__global__ __launch_bounds__(256) void k_blocksum(const int* __restrict__ cnt,
                                                  int* __restrict__ partial, int N) {
    __shared__ int s[256];
    int t = threadIdx.x;
    int i = blockIdx.x * 256 + t;
    s[t] = (i < N) ? cnt[i] : 0;
    __syncthreads();
    for (int st = 128; st; st >>= 1) {
        if (t < st) s[t] += s[t + st];
        __syncthreads();
    }
    if (t == 0) partial[blockIdx.x] = s[0];
}

__global__ __launch_bounds__(1024) void k_scan_partials(int* __restrict__ partial, int NB) {
    __shared__ int s[1024];
    int t = threadIdx.x;
    s[t] = (t < NB) ? partial[t] : 0;
    __syncthreads();
    for (int off = 1; off < 1024; off <<= 1) {
        int u = (t >= off) ? s[t - off] : 0;
        __syncthreads();
        s[t] += u;
        __syncthreads();
    }
    if (t < NB) partial[t] = (t == 0) ? 0 : s[t - 1];   // exclusive
}

// per-block exclusive scan + global offset; also dinv and cursor init
__global__ __launch_bounds__(256) void k_rowstart(const int* __restrict__ cnt,
                                                  const int* __restrict__ partial,
                                                  int* __restrict__ rowstart,
                                                  int* __restrict__ cursor,
                                                  float* __restrict__ dinv,
                                                  int N, int E) {
    __shared__ int s[256];
    int t = threadIdx.x;
    int i = blockIdx.x * 256 + t;
    int v = (i < N) ? cnt[i] : 0;
    s[t] = v;
    __syncthreads();
    for (int off = 1; off < 256; off <<= 1) {
        int u = (t >= off) ? s[t - off] : 0;
        __syncthreads();
        s[t] += u;
        __syncthreads();
    }
    if (i < N) {
        int rs = partial[blockIdx.x] + s[t] - v;   // exclusive
        rowstart[i] = rs;
        cursor[i] = rs;
        dinv[i] = rsqrtf((float)(v + 1));          // deg = in-degree + self-loop
    }
    if (blockIdx.x == 0 && t == 0) rowstart[N] = E;
}

__global__ void k_scatter(const int* __restrict__ src, const int* __restrict__ dst,
                          int* __restrict__ cursor, int* __restrict__ csr, int E) {
    int e = blockIdx.x * 256 + threadIdx.x;
    if (e < E) {
        int p = atomicAdd(&cursor[dst[e]], 1);
        csr[p] = src[e];
    }
}

// ---------------- gather aggregation: out = Âx (C=64), one wave per node ----------------
template<bool BIAS>
__global__ __launch_bounds__(256) void k_gather64(const int* __restrict__ rowstart,
                                                  const int* __restrict__ csr,
                                                  const float* __restrict__ dinv,
                                                  const float* __restrict__ xw,
                                                  const float* __restrict__ bias,
                                                  float* __restrict__ out, int N) {
    const int node = blockIdx.x * 4 + (threadIdx.x >> 6);
    const int f = threadIdx.x & 63;
    if (node >= N) return;
    const int rs = rowstart[node];
    const int re = rowstart[node + 1];

    float acc = 0.0f;
    for (int base = rs; base < re; base += 64) {
        int idx = base + f;
        int sE = (idx < re) ? csr[idx] : 0;
        float dE = (idx < re) ? dinv[sE] : 0.0f;
        int cnt = re - base; if (cnt > 64) cnt = 64;
        for (int k = 0; k < cnt; ++k) {
            int sk = __shfl(sE, k);
            float dk = __shfl(dE, k);
            acc += dk * xw[(size_t)sk * 64 + f];
        }
    }
    float dd = dinv[node];
    float v = dd * acc + dd * dd * xw[(size_t)node * 64 + f];
    if (BIAS) v += bias[f];
    out[(size_t)node * 64 + f] = v;
}

// ---------------- GEMM: Y[N,C] = X[N,K] @ W[K,C] (+bias, +relu optional) ----------------
template<int K, int C, bool BIAS, bool RELU>
__global__ __launch_bounds__(256) void k_gemm(const float* __restrict__ X,
                                              const float* __restrict__ W,
                                              const float* __restrict__ bias,
                                              float* __restrict__ Y, int N) {
    constexpr int ROWS = 64;
    __shared__ float sW[K * C];
    __shared__ float sX[ROWS * K];
    const int t = threadIdx.x;
    const int row0 = blockIdx.x * ROWS;

    for (int i = t; i < K * C; i += 256) sW[i] = W[i];
    for (int i = t; i < ROWS * K; i += 256) {
        int r = i / K, k = i - r * K;
        int row = row0 + r;
        sX[i] = (row < N) ? X[(size_t)row * K + k] : 0.0f;
    }
    __syncthreads();

    for (int i = t; i < ROWS * C; i += 256) {
        int r = i / C, c = i - r * C;
        int row = row0 + r;
        if (row < N) {
            float acc = BIAS ? bias[c] : 0.0f;
            #pragma unroll 8
            for (int k = 0; k < K; ++k) acc += sX[r * K + k] * sW[k * C + c];
            if (RELU) acc = fmaxf(acc, 0.0f);
            Y[(size_t)row * C + c] = acc;
        }
    }
}

// ---------------- MLP head: one wave (64 threads) per output row ----------------
__global__ __launch_bounds__(64) void k_mlp(const float* __restrict__ h,
                                            const int* __restrict__ ui,
                                            const int* __restrict__ ii,
                                            const float* __restrict__ fcW1, const float* __restrict__ fcb1,
                                            const float* __restrict__ g1,   const float* __restrict__ be1,
                                            const float* __restrict__ fcW2, const float* __restrict__ fcb2,
                                            const float* __restrict__ g2,   const float* __restrict__ be2,
                                            const float* __restrict__ fcW3, const float* __restrict__ fcb3,
                                            float* __restrict__ out, int nUsers) {
    const int b = blockIdx.x;
    const int lane = threadIdx.x;   // 0..63
    __shared__ float sc[128];
    __shared__ float sz[128];

    const int u  = ui[b] - 1;
    const int it = nUsers + ii[b] - 1;
    sc[lane]      = h[(size_t)u  * 64 + lane];
    sc[lane + 64] = h[(size_t)it * 64 + lane];
    __syncthreads();

    // fc1: 128 -> 128, each lane computes outputs lane and lane+64
    float v0 = fcb1[lane], v1 = fcb1[lane + 64];
    #pragma unroll 4
    for (int k = 0; k < 128; ++k) {
        float ck = sc[k];
        v0 += ck * fcW1[k * 128 + lane];
        v1 += ck * fcW1[k * 128 + lane + 64];
    }
    float s = v0 + v1;
    float ss = v0 * v0 + v1 * v1;
    #pragma unroll
    for (int m = 32; m; m >>= 1) { s += __shfl_xor(s, m); ss += __shfl_xor(ss, m); }
    float mu  = s * (1.0f / 128.0f);
    float var = ss * (1.0f / 128.0f) - mu * mu;
    float rs  = rsqrtf(var + 1e-5f);
    v0 = (v0 - mu) * rs * g1[lane]      + be1[lane];      v0 = fmaxf(v0, 0.0f);
    v1 = (v1 - mu) * rs * g1[lane + 64] + be1[lane + 64]; v1 = fmaxf(v1, 0.0f);
    sz[lane] = v0; sz[lane + 64] = v1;
    __syncthreads();

    // fc2: 128 -> 64, one output per lane
    float w = fcb2[lane];
    #pragma unroll 4
    for (int k = 0; k < 128; ++k) w += sz[k] * fcW2[k * 64 + lane];
    s = w; ss = w * w;
    #pragma unroll
    for (int m = 32; m; m >>= 1) { s += __shfl_xor(s, m); ss += __shfl_xor(ss, m); }
    mu  = s * (1.0f / 64.0f);
    var = ss * (1.0f / 64.0f) - mu * mu;
    rs  = rsqrtf(var + 1e-5f);
    w = (w - mu) * rs * g2[lane] + be2[lane];
    w = fmaxf(w, 0.0f);

    // fc3: 64 -> 1 dot + sigmoid
    float p = w * fcW3[lane];
    #pragma unroll
    for (int m = 32; m; m >>= 1) p += __shfl_xor(p, m);
    if (lane == 0) out[b] = 1.0f / (1.0f + expf(-(p + fcb3[0])));
}

extern "C" void kernel_launch(void* const* d_in, const int* in_sizes, int n_in,
                              void* d_out, int out_size, void* d_ws, size_t ws_size,
                              hipStream_t stream) {
    const float* x    = (const float*)d_in[0];
    const int*   src  = (const int*)d_in[1];
    const int*   dst  = (const int*)d_in[2];
    const int*   ui   = (const int*)d_in[3];
    const int*   ii   = (const int*)d_in[4];
    const float* W1   = (const float*)d_in[5];
    const float* b1   = (const float*)d_in[6];
    const float* W2   = (const float*)d_in[7];
    const float* b2   = (const float*)d_in[8];
    const float* fcW1 = (const float*)d_in[9];
    const float* fcb1 = (const float*)d_in[10];
    const float* g1   = (const float*)d_in[11];
    const float* be1  = (const float*)d_in[12];
    const float* fcW2 = (const float*)d_in[13];
    const float* fcb2 = (const float*)d_in[14];
    const float* g2   = (const float*)d_in[15];
    const float* be2  = (const float*)d_in[16];
    const float* fcW3 = (const float*)d_in[17];
    const float* fcb3 = (const float*)d_in[18];
    float* out = (float*)d_out;

    const int N = in_sizes[0] / 64;   // 150000
    const int E = in_sizes[1];        // 2400000
    const int B = in_sizes[3];        // 16384
    const int NB = (N + 255) / 256;   // 586 <= 1024

    // ---- workspace layout ----
    float* ws    = (float*)d_ws;
    float* dinv  = ws;                               // N
    float* bufC  = dinv + N;                         // N*64  : aggX, then xw2
    float* bufH  = bufC + (size_t)N * 64;            // N*128 : h1, then h2 (first N*64)
    int*   cnt      = (int*)(bufH + (size_t)N * 128);// N
    int*   rowstart = cnt + N;                       // N+1
    int*   cursor   = rowstart + N + 1;              // N
    int*   csr      = cursor + N;                    // E
    int*   partial  = csr + E;                       // 1024

    // ---- CSR build (counting sort by dst) + dinv ----
    k_zero_i<<<NB, 256, 0, stream>>>(cnt, N);
    k_hist<<<(E + 255) / 256, 256, 0, stream>>>(dst, cnt, E);
    k_blocksum<<<NB, 256, 0, stream>>>(cnt, partial, N);
    k_scan_partials<<<1, 1024, 0, stream>>>(partial, NB);
    k_rowstart<<<NB, 256, 0, stream>>>(cnt, partial, rowstart, cursor, dinv, N, E);
    k_scatter<<<(E + 255) / 256, 256, 0, stream>>>(src, dst, cursor, csr, E);

    // ---- layer 1: h1 = relu((A_hat x) @ W1 + b1) ----
    k_gather64<false><<<(N + 3) / 4, 256, 0, stream>>>(rowstart, csr, dinv, x, nullptr, bufC, N);
    k_gemm<64, 128, true, true><<<(N + 63) / 64, 256, 0, stream>>>(bufC, W1, b1, bufH, N);

    // ---- layer 2: h2 = A_hat (h1 @ W2) + b2 ----
    k_gemm<128, 64, false, false><<<(N + 63) / 64, 256, 0, stream>>>(bufH, W2, nullptr, bufC, N);
    k_gather64<true><<<(N + 3) / 4, 256, 0, stream>>>(rowstart, csr, dinv, bufC, b2, bufH, N);

    // ---- MLP head ----
    k_mlp<<<B, 64, 0, stream>>>(bufH, ui, ii,
                                fcW1, fcb1, g1, be1,
                                fcW2, fcb2, g2, be2,
                                fcW3, fcb3, out, N_USERS_C);
}

// Round 3
// 688.149 us; speedup vs baseline: 3.2086x; 1.5872x over previous
//
#include <hip/hip_runtime.h>
#include <hip/hip_bf16.h>
#include <math.h>

#define N_USERS_C 100000
#define BK_SHIFT 9
#define BK_NODES 512

// ---------------- small helpers ----------------
__global__ void k_zero_i(int* __restrict__ p, int n) {
    int i = blockIdx.x * 256 + threadIdx.x;
    if (i < n) p[i] = 0;
}

// ---------------- pass 0: coarse histogram over buckets ----------------
__global__ __launch_bounds__(512) void k_binCount(const int* __restrict__ dst,
                                                  int* __restrict__ chist, int E, int nbk) {
    __shared__ int lcnt[BK_NODES];
    int t = threadIdx.x;
    for (int i = t; i < nbk; i += 512) lcnt[i] = 0;
    __syncthreads();
    int e0 = blockIdx.x * 2048;
    #pragma unroll
    for (int j = 0; j < 4; ++j) {
        int e = e0 + j * 512 + t;
        if (e < E) atomicAdd(&lcnt[dst[e] >> BK_SHIFT], 1);
    }
    __syncthreads();
    for (int i = t; i < nbk; i += 512)
        if (lcnt[i]) atomicAdd(&chist[i], lcnt[i]);
}

// ---------------- scan buckets -> bucketBase, cursor; rowstart[N]=E ----------------
__global__ __launch_bounds__(512) void k_scanChist(const int* __restrict__ chist,
                                                   int* __restrict__ base,
                                                   int* __restrict__ cursor,
                                                   int* __restrict__ rowstart,
                                                   int nbk, int N, int E) {
    __shared__ int s[512];
    int t = threadIdx.x;
    int v = (t < nbk) ? chist[t] : 0;
    s[t] = v;
    __syncthreads();
    for (int off = 1; off < 512; off <<= 1) {
        int u = (t >= off) ? s[t - off] : 0;
        __syncthreads();
        s[t] += u;
        __syncthreads();
    }
    int ex = s[t] - v;
    if (t < nbk) { base[t] = ex; cursor[t] = ex; }
    if (t == 0) { base[nbk] = E; rowstart[N] = E; }
}

// ---------------- pass 1: block-local counting sort into bucket regions ----------------
__global__ __launch_bounds__(512) void k_bin(const int* __restrict__ src,
                                             const int* __restrict__ dst,
                                             int* __restrict__ bucketCursor,
                                             int* __restrict__ pairBuf, int E, int nbk) {
    __shared__ int lcnt[BK_NODES];
    __shared__ int scanS[512];
    __shared__ int lofs[BK_NODES];
    __shared__ int delta[BK_NODES];
    __shared__ int sPack[2048];
    __shared__ unsigned short sBkt[2048];
    int t = threadIdx.x;
    int e0 = blockIdx.x * 2048;
    for (int i = t; i < nbk; i += 512) lcnt[i] = 0;
    __syncthreads();

    int mySrc[4], myB[4], myDl[4];
    #pragma unroll
    for (int j = 0; j < 4; ++j) {
        int e = e0 + j * 512 + t;
        if (e < E) {
            int sv = src[e], dv = dst[e];
            mySrc[j] = sv; myB[j] = dv >> BK_SHIFT; myDl[j] = dv & (BK_NODES - 1);
            atomicAdd(&lcnt[myB[j]], 1);
        } else myB[j] = -1;
    }
    __syncthreads();
    // exclusive scan of lcnt[0..nbk)
    int v = (t < nbk) ? lcnt[t] : 0;
    scanS[t] = v;
    __syncthreads();
    for (int off = 1; off < 512; off <<= 1) {
        int u = (t >= off) ? scanS[t - off] : 0;
        __syncthreads();
        scanS[t] += u;
        __syncthreads();
    }
    if (t < nbk) lofs[t] = scanS[t] - v;
    __syncthreads();
    // reserve global ranges
    if (t < nbk) {
        int c = lcnt[t];
        int gb = (c > 0) ? atomicAdd(&bucketCursor[t], c) : 0;
        delta[t] = gb - lofs[t];
    }
    __syncthreads();
    // place into LDS ordered by bucket
    #pragma unroll
    for (int j = 0; j < 4; ++j) {
        if (myB[j] >= 0) {
            int p = atomicAdd(&lofs[myB[j]], 1);
            sPack[p] = mySrc[j] | (myDl[j] << 18);   // src < 2^18
            sBkt[p] = (unsigned short)myB[j];
        }
    }
    __syncthreads();
    // coalesced copy out (contiguous per bucket run)
    int total = (E - e0 < 2048) ? (E - e0) : 2048;
    for (int i = t; i < total; i += 512)
        pairBuf[delta[sBkt[i]] + i] = sPack[i];
}

// ---------------- pass 2: per-bucket node hist/scan -> rowstart,dinv; scatter csr ----------------
__global__ __launch_bounds__(256) void k_bscatter(const int* __restrict__ pairBuf,
                                                  const int* __restrict__ base,
                                                  int* __restrict__ rowstart,
                                                  float* __restrict__ dinv,
                                                  int* __restrict__ csr, int N) {
    int b = blockIdx.x;
    int n0 = b << BK_SHIFT;
    int n1 = n0 + BK_NODES; if (n1 > N) n1 = N;
    int nn = n1 - n0;
    __shared__ int hist[BK_NODES];
    __shared__ int curs[BK_NODES];
    __shared__ int ps[256];
    int t = threadIdx.x;
    for (int i = t; i < nn; i += 256) hist[i] = 0;
    __syncthreads();
    int e0 = base[b], e1 = base[b + 1];
    for (int e = e0 + t; e < e1; e += 256)
        atomicAdd(&hist[pairBuf[e] >> 18], 1);
    __syncthreads();
    // exclusive scan over nn (<=512) entries, 2 per thread
    int h0 = (2 * t < nn) ? hist[2 * t] : 0;
    int h1 = (2 * t + 1 < nn) ? hist[2 * t + 1] : 0;
    int p = h0 + h1;
    ps[t] = p;
    __syncthreads();
    for (int off = 1; off < 256; off <<= 1) {
        int u = (t >= off) ? ps[t - off] : 0;
        __syncthreads();
        ps[t] += u;
        __syncthreads();
    }
    int ex = ps[t] - p;
    if (2 * t < nn) {
        int r0 = e0 + ex;
        rowstart[n0 + 2 * t] = r0; curs[2 * t] = r0;
        dinv[n0 + 2 * t] = rsqrtf((float)(h0 + 1));
    }
    if (2 * t + 1 < nn) {
        int r1 = e0 + ex + h0;
        rowstart[n0 + 2 * t + 1] = r1; curs[2 * t + 1] = r1;
        dinv[n0 + 2 * t + 1] = rsqrtf((float)(h1 + 1));
    }
    __syncthreads();
    for (int e = e0 + t; e < e1; e += 256) {
        int pk = pairBuf[e];
        int pos = atomicAdd(&curs[pk >> 18], 1);
        csr[pos] = pk & 0x3FFFF;
    }
}

// ---------------- gather aggregation: out = Âx (C=64), one wave per node ----------------
template<bool BIAS>
__global__ __launch_bounds__(256) void k_gather64(const int* __restrict__ rowstart,
                                                  const int* __restrict__ csr,
                                                  const float* __restrict__ dinv,
                                                  const float* __restrict__ xw,
                                                  const float* __restrict__ bias,
                                                  float* __restrict__ out, int N) {
    const int node = blockIdx.x * 4 + (threadIdx.x >> 6);
    const int f = threadIdx.x & 63;
    if (node >= N) return;
    const int rs = rowstart[node];
    const int re = rowstart[node + 1];

    float acc = 0.0f;
    for (int base = rs; base < re; base += 64) {
        int idx = base + f;
        int sE = (idx < re) ? csr[idx] : 0;
        float dE = (idx < re) ? dinv[sE] : 0.0f;
        int cnt = re - base; if (cnt > 64) cnt = 64;
        for (int k = 0; k < cnt; ++k) {
            int sk = __shfl(sE, k);
            float dk = __shfl(dE, k);
            acc += dk * xw[(size_t)sk * 64 + f];
        }
    }
    float dd = dinv[node];
    float v = dd * acc + dd * dd * xw[(size_t)node * 64 + f];
    if (BIAS) v += bias[f];
    out[(size_t)node * 64 + f] = v;
}

// ---------------- register-tiled GEMM: Y[:, c0:c0+64] = X[N,K] @ W[K,ldw] ----------------
// 256 threads = 16 row-groups x 16 col-groups; thread computes 4 rows x 4 cols.
template<int K, bool BIAS, bool RELU>
__global__ __launch_bounds__(256) void k_gemm64(const float* __restrict__ X,
                                                const float* __restrict__ W, int ldw,
                                                const float* __restrict__ bias,
                                                float* __restrict__ Y, int ldy, int N) {
    __shared__ float sX[64 * K];    // [64][K] row-major
    __shared__ float sW[K * 64];    // [K][64]
    const int t = threadIdx.x;
    const int row0 = blockIdx.x * 64;
    const int c0 = blockIdx.y * 64;
    constexpr int KQ = K / 4;

    for (int i = t; i < K * 16; i += 256) {       // W tile: K*64/4 float4s
        int k = i >> 4, cq = i & 15;
        *(float4*)&sW[k * 64 + cq * 4] = *(const float4*)&W[(size_t)k * ldw + c0 + cq * 4];
    }
    for (int i = t; i < K * 16; i += 256) {       // X tile: 64*K/4 float4s
        int r = i / KQ, kq = i - r * KQ;
        int row = row0 + r;
        float4 xv = (row < N) ? *(const float4*)&X[(size_t)row * K + kq * 4]
                              : make_float4(0.f, 0.f, 0.f, 0.f);
        *(float4*)&sX[r * K + kq * 4] = xv;
    }
    __syncthreads();

    const int rg = t >> 4;
    const int cg = t & 15;
    float acc[4][4];
    float binit[4] = {0.f, 0.f, 0.f, 0.f};
    if (BIAS) {
        float4 bv = *(const float4*)&bias[c0 + cg * 4];
        binit[0] = bv.x; binit[1] = bv.y; binit[2] = bv.z; binit[3] = bv.w;
    }
    #pragma unroll
    for (int j = 0; j < 4; ++j)
        #pragma unroll
        for (int c = 0; c < 4; ++c) acc[j][c] = binit[c];

    #pragma unroll 4
    for (int k = 0; k < K; ++k) {
        float4 wv = *(const float4*)&sW[k * 64 + cg * 4];
        #pragma unroll
        for (int j = 0; j < 4; ++j) {
            float xr = sX[(rg * 4 + j) * K + k];
            acc[j][0] += xr * wv.x;
            acc[j][1] += xr * wv.y;
            acc[j][2] += xr * wv.z;
            acc[j][3] += xr * wv.w;
        }
    }

    #pragma unroll
    for (int j = 0; j < 4; ++j) {
        int row = row0 + rg * 4 + j;
        if (row < N) {
            float4 o;
            o.x = RELU ? fmaxf(acc[j][0], 0.f) : acc[j][0];
            o.y = RELU ? fmaxf(acc[j][1], 0.f) : acc[j][1];
            o.z = RELU ? fmaxf(acc[j][2], 0.f) : acc[j][2];
            o.w = RELU ? fmaxf(acc[j][3], 0.f) : acc[j][3];
            *(float4*)&Y[(size_t)row * ldy + c0 + cg * 4] = o;
        }
    }
}

// ---------------- concat gather: cB[b][0:64]=h[u], [64:128]=h[item] ----------------
__global__ void k_concat(const float* __restrict__ h, const int* __restrict__ ui,
                         const int* __restrict__ ii, float* __restrict__ cB, int B) {
    int i = blockIdx.x * 256 + threadIdx.x;
    if (i >= B * 128) return;
    int b = i >> 7, j = i & 127;
    int node = (j < 64) ? (ui[b] - 1) : (N_USERS_C + ii[b] - 1);
    cB[i] = h[(size_t)node * 64 + (j & 63)];
}

// ---------------- LayerNorm (+ReLU) in place, one wave per row ----------------
template<int C, bool RELU>
__global__ __launch_bounds__(256) void k_ln(float* __restrict__ z, const float* __restrict__ g,
                                            const float* __restrict__ be, int B) {
    int row = blockIdx.x * 4 + (threadIdx.x >> 6);
    int lane = threadIdx.x & 63;
    if (row >= B) return;
    float* zr = z + (size_t)row * C;
    float v0 = zr[lane];
    float v1 = (C == 128) ? zr[lane + 64] : 0.0f;
    float s = v0 + v1, ss = v0 * v0 + v1 * v1;
    #pragma unroll
    for (int m = 32; m; m >>= 1) { s += __shfl_xor(s, m); ss += __shfl_xor(ss, m); }
    float mu = s * (1.0f / C);
    float var = ss * (1.0f / C) - mu * mu;
    float rs = rsqrtf(var + 1e-5f);
    float o0 = (v0 - mu) * rs * g[lane] + be[lane];
    if (RELU) o0 = fmaxf(o0, 0.f);
    zr[lane] = o0;
    if (C == 128) {
        float o1 = (v1 - mu) * rs * g[lane + 64] + be[lane + 64];
        if (RELU) o1 = fmaxf(o1, 0.f);
        zr[lane + 64] = o1;
    }
}

// ---------------- head: dot(z2,w3)+b3 -> sigmoid ----------------
__global__ __launch_bounds__(256) void k_head(const float* __restrict__ z2,
                                              const float* __restrict__ w3,
                                              const float* __restrict__ b3,
                                              float* __restrict__ out, int B) {
    int row = blockIdx.x * 4 + (threadIdx.x >> 6);
    int lane = threadIdx.x & 63;
    if (row >= B) return;
    float p = z2[(size_t)row * 64 + lane] * w3[lane];
    #pragma unroll
    for (int m = 32; m; m >>= 1) p += __shfl_xor(p, m);
    if (lane == 0) out[row] = 1.0f / (1.0f + expf(-(p + b3[0])));
}

extern "C" void kernel_launch(void* const* d_in, const int* in_sizes, int n_in,
                              void* d_out, int out_size, void* d_ws, size_t ws_size,
                              hipStream_t stream) {
    const float* x    = (const float*)d_in[0];
    const int*   src  = (const int*)d_in[1];
    const int*   dst  = (const int*)d_in[2];
    const int*   ui   = (const int*)d_in[3];
    const int*   ii   = (const int*)d_in[4];
    const float* W1   = (const float*)d_in[5];
    const float* b1   = (const float*)d_in[6];
    const float* W2   = (const float*)d_in[7];
    const float* b2   = (const float*)d_in[8];
    const float* fcW1 = (const float*)d_in[9];
    const float* fcb1 = (const float*)d_in[10];
    const float* g1   = (const float*)d_in[11];
    const float* be1  = (const float*)d_in[12];
    const float* fcW2 = (const float*)d_in[13];
    const float* fcb2 = (const float*)d_in[14];
    const float* g2   = (const float*)d_in[15];
    const float* be2  = (const float*)d_in[16];
    const float* fcW3 = (const float*)d_in[17];
    const float* fcb3 = (const float*)d_in[18];
    float* out = (float*)d_out;

    const int N = in_sizes[0] / 64;          // 150000
    const int E = in_sizes[1];               // 2400000
    const int B = in_sizes[3];               // 16384
    const int NBK = (N + BK_NODES - 1) >> BK_SHIFT;   // 293
    const int EB = (E + 2047) / 2048;        // edge blocks

    // ---- workspace layout ----
    float* ws   = (float*)d_ws;
    float* dinv = ws;                                   // N
    float* bufC = dinv + N;                             // N*64
    float* bufH = bufC + (size_t)N * 64;                // N*128
    int* rowstart = (int*)(bufH + (size_t)N * 128);     // N+1
    int* csr      = rowstart + (N + 1);                 // E
    int* pairBuf  = csr + E;                            // E
    int* chist    = pairBuf + E;                        // 512
    int* bbase    = chist + 512;                        // 513
    int* bcursor  = bbase + 513;                        // 512
    // MLP buffers alias bufC (free after k_concat input is bufH)
    float* cB = bufC;                 // B*128
    float* z1 = cB + (size_t)B * 128; // B*128
    float* z2 = z1 + (size_t)B * 128; // B*64   (total 5.24M <= N*64=9.6M)

    // ---- CSR build: coarse hist -> scan -> bin -> per-bucket scatter ----
    k_zero_i<<<2, 256, 0, stream>>>(chist, 512);
    k_binCount<<<EB, 512, 0, stream>>>(dst, chist, E, NBK);
    k_scanChist<<<1, 512, 0, stream>>>(chist, bbase, bcursor, rowstart, NBK, N, E);
    k_bin<<<EB, 512, 0, stream>>>(src, dst, bcursor, pairBuf, E, NBK);
    k_bscatter<<<NBK, 256, 0, stream>>>(pairBuf, bbase, rowstart, dinv, csr, N);

    // ---- layer 1: h1 = relu((A_hat x) @ W1 + b1) ----
    k_gather64<false><<<(N + 3) / 4, 256, 0, stream>>>(rowstart, csr, dinv, x, nullptr, bufC, N);
    k_gemm64<64, true, true><<<dim3((N + 63) / 64, 2), 256, 0, stream>>>(bufC, W1, 128, b1, bufH, 128, N);

    // ---- layer 2: h2 = A_hat (h1 @ W2) + b2 ----
    k_gemm64<128, false, false><<<dim3((N + 63) / 64, 1), 256, 0, stream>>>(bufH, W2, 64, nullptr, bufC, 64, N);
    k_gather64<true><<<(N + 3) / 4, 256, 0, stream>>>(rowstart, csr, dinv, bufC, b2, bufH, N);

    // ---- MLP head as GEMMs ----
    k_concat<<<(B * 128 + 255) / 256, 256, 0, stream>>>(bufH, ui, ii, cB, B);
    k_gemm64<128, true, false><<<dim3(B / 64, 2), 256, 0, stream>>>(cB, fcW1, 128, fcb1, z1, 128, B);
    k_ln<128, true><<<(B + 3) / 4, 256, 0, stream>>>(z1, g1, be1, B);
    k_gemm64<128, true, false><<<dim3(B / 64, 1), 256, 0, stream>>>(z1, fcW2, 64, fcb2, z2, 64, B);
    k_ln<64, true><<<(B + 3) / 4, 256, 0, stream>>>(z2, g2, be2, B);
    k_head<<<(B + 3) / 4, 256, 0, stream>>>(z2, fcW3, fcb3, out, B);
}

// Round 4
// 559.009 us; speedup vs baseline: 3.9498x; 1.2310x over previous
//
#include <hip/hip_runtime.h>
#include <hip/hip_bf16.h>
#include <math.h>

#define N_USERS_C 100000
#define BK_SHIFT 9
#define BK_NODES 512

// ---------------- small helpers ----------------
__global__ void k_zero_i(int* __restrict__ p, int n) {
    int i = blockIdx.x * 256 + threadIdx.x;
    if (i < n) p[i] = 0;
}

// ---------------- pass 0: coarse histogram over buckets ----------------
__global__ __launch_bounds__(512) void k_binCount(const int* __restrict__ dst,
                                                  int* __restrict__ chist, int E, int nbk) {
    __shared__ int lcnt[BK_NODES];
    int t = threadIdx.x;
    for (int i = t; i < nbk; i += 512) lcnt[i] = 0;
    __syncthreads();
    int e0 = blockIdx.x * 2048;
    #pragma unroll
    for (int j = 0; j < 4; ++j) {
        int e = e0 + j * 512 + t;
        if (e < E) atomicAdd(&lcnt[dst[e] >> BK_SHIFT], 1);
    }
    __syncthreads();
    for (int i = t; i < nbk; i += 512)
        if (lcnt[i]) atomicAdd(&chist[i], lcnt[i]);
}

// ---------------- scan buckets -> bucketBase, cursor; rowstart[N]=E ----------------
__global__ __launch_bounds__(512) void k_scanChist(const int* __restrict__ chist,
                                                   int* __restrict__ base,
                                                   int* __restrict__ cursor,
                                                   int* __restrict__ rowstart,
                                                   int nbk, int N, int E) {
    __shared__ int s[512];
    int t = threadIdx.x;
    int v = (t < nbk) ? chist[t] : 0;
    s[t] = v;
    __syncthreads();
    for (int off = 1; off < 512; off <<= 1) {
        int u = (t >= off) ? s[t - off] : 0;
        __syncthreads();
        s[t] += u;
        __syncthreads();
    }
    int ex = s[t] - v;
    if (t < nbk) { base[t] = ex; cursor[t] = ex; }
    if (t == 0) { base[nbk] = E; rowstart[N] = E; }
}

// ---------------- pass 1: block-local counting sort into bucket regions ----------------
__global__ __launch_bounds__(512) void k_bin(const int* __restrict__ src,
                                             const int* __restrict__ dst,
                                             int* __restrict__ bucketCursor,
                                             int* __restrict__ pairBuf, int E, int nbk) {
    __shared__ int lcnt[BK_NODES];
    __shared__ int scanS[512];
    __shared__ int lofs[BK_NODES];
    __shared__ int delta[BK_NODES];
    __shared__ int sPack[2048];
    __shared__ unsigned short sBkt[2048];
    int t = threadIdx.x;
    int e0 = blockIdx.x * 2048;
    for (int i = t; i < nbk; i += 512) lcnt[i] = 0;
    __syncthreads();

    int mySrc[4], myB[4], myDl[4];
    #pragma unroll
    for (int j = 0; j < 4; ++j) {
        int e = e0 + j * 512 + t;
        if (e < E) {
            int sv = src[e], dv = dst[e];
            mySrc[j] = sv; myB[j] = dv >> BK_SHIFT; myDl[j] = dv & (BK_NODES - 1);
            atomicAdd(&lcnt[myB[j]], 1);
        } else myB[j] = -1;
    }
    __syncthreads();
    int v = (t < nbk) ? lcnt[t] : 0;
    scanS[t] = v;
    __syncthreads();
    for (int off = 1; off < 512; off <<= 1) {
        int u = (t >= off) ? scanS[t - off] : 0;
        __syncthreads();
        scanS[t] += u;
        __syncthreads();
    }
    if (t < nbk) lofs[t] = scanS[t] - v;
    __syncthreads();
    if (t < nbk) {
        int c = lcnt[t];
        int gb = (c > 0) ? atomicAdd(&bucketCursor[t], c) : 0;
        delta[t] = gb - lofs[t];
    }
    __syncthreads();
    #pragma unroll
    for (int j = 0; j < 4; ++j) {
        if (myB[j] >= 0) {
            int p = atomicAdd(&lofs[myB[j]], 1);
            sPack[p] = mySrc[j] | (myDl[j] << 18);   // src < 2^18
            sBkt[p] = (unsigned short)myB[j];
        }
    }
    __syncthreads();
    int total = (E - e0 < 2048) ? (E - e0) : 2048;
    for (int i = t; i < total; i += 512)
        pairBuf[delta[sBkt[i]] + i] = sPack[i];
}

// ---------------- pass 2: per-bucket node hist/scan -> rowstart,dinv; scatter csr ----------------
__global__ __launch_bounds__(256) void k_bscatter(const int* __restrict__ pairBuf,
                                                  const int* __restrict__ base,
                                                  int* __restrict__ rowstart,
                                                  float* __restrict__ dinv,
                                                  int* __restrict__ csr, int N) {
    int b = blockIdx.x;
    int n0 = b << BK_SHIFT;
    int n1 = n0 + BK_NODES; if (n1 > N) n1 = N;
    int nn = n1 - n0;
    __shared__ int hist[BK_NODES];
    __shared__ int curs[BK_NODES];
    __shared__ int ps[256];
    int t = threadIdx.x;
    for (int i = t; i < nn; i += 256) hist[i] = 0;
    __syncthreads();
    int e0 = base[b], e1 = base[b + 1];
    for (int e = e0 + t; e < e1; e += 256)
        atomicAdd(&hist[pairBuf[e] >> 18], 1);
    __syncthreads();
    int h0 = (2 * t < nn) ? hist[2 * t] : 0;
    int h1 = (2 * t + 1 < nn) ? hist[2 * t + 1] : 0;
    int p = h0 + h1;
    ps[t] = p;
    __syncthreads();
    for (int off = 1; off < 256; off <<= 1) {
        int u = (t >= off) ? ps[t - off] : 0;
        __syncthreads();
        ps[t] += u;
        __syncthreads();
    }
    int ex = ps[t] - p;
    if (2 * t < nn) {
        int r0 = e0 + ex;
        rowstart[n0 + 2 * t] = r0; curs[2 * t] = r0;
        dinv[n0 + 2 * t] = rsqrtf((float)(h0 + 1));
    }
    if (2 * t + 1 < nn) {
        int r1 = e0 + ex + h0;
        rowstart[n0 + 2 * t + 1] = r1; curs[2 * t + 1] = r1;
        dinv[n0 + 2 * t + 1] = rsqrtf((float)(h1 + 1));
    }
    __syncthreads();
    for (int e = e0 + t; e < e1; e += 256) {
        int pk = pairBuf[e];
        int pos = atomicAdd(&curs[pk >> 18], 1);
        csr[pos] = pk & 0x3FFFF;
    }
}

// ---------------- gather1: aggX = A_hat x (C=64), one wave per node ----------------
__global__ __launch_bounds__(256) void k_gather64(const int* __restrict__ rowstart,
                                                  const int* __restrict__ csr,
                                                  const float* __restrict__ dinv,
                                                  const float* __restrict__ xw,
                                                  float* __restrict__ out, int N) {
    const int node = blockIdx.x * 4 + (threadIdx.x >> 6);
    const int f = threadIdx.x & 63;
    if (node >= N) return;
    const int rs = rowstart[node];
    const int re = rowstart[node + 1];

    float acc = 0.0f;
    for (int base = rs; base < re; base += 64) {
        int idx = base + f;
        int sE = (idx < re) ? csr[idx] : 0;
        float dE = (idx < re) ? dinv[sE] : 0.0f;
        int cnt = re - base; if (cnt > 64) cnt = 64;
        for (int k = 0; k < cnt; ++k) {
            int sk = __shfl(sE, k);
            float dk = __shfl(dE, k);
            acc += dk * xw[(size_t)sk * 64 + f];
        }
    }
    float dd = dinv[node];
    out[(size_t)node * 64 + f] = dd * acc + dd * dd * xw[(size_t)node * 64 + f];
}

// ---------------- pruned gather2 + concat: cB[b] = [h2(user), h2(item)] ----------------
// xs2 = dinv[row] * (h1@W2) is pre-scaled; h2 = dd*(sum_e xs2[src] + xs2[node]) + b2
__global__ __launch_bounds__(128) void k_gather_pairs(const int* __restrict__ rowstart,
                                                      const int* __restrict__ csr,
                                                      const float* __restrict__ dinv,
                                                      const float* __restrict__ xs2,
                                                      const float* __restrict__ b2,
                                                      const int* __restrict__ ui,
                                                      const int* __restrict__ ii,
                                                      float* __restrict__ cB, int B) {
    const int b = blockIdx.x;
    const int half = threadIdx.x >> 6;
    const int f = threadIdx.x & 63;
    const int node = (half == 0) ? (ui[b] - 1) : (N_USERS_C + ii[b] - 1);
    const int rs = rowstart[node];
    const int re = rowstart[node + 1];

    float acc = 0.0f;
    for (int base = rs; base < re; base += 64) {
        int idx = base + f;
        int sE = (idx < re) ? csr[idx] : 0;
        int cnt = re - base; if (cnt > 64) cnt = 64;
        for (int k = 0; k < cnt; ++k) {
            int sk = __shfl(sE, k);
            acc += xs2[(size_t)sk * 64 + f];
        }
    }
    float dd = dinv[node];
    cB[(size_t)b * 128 + half * 64 + f] =
        dd * (acc + xs2[(size_t)node * 64 + f]) + b2[f];
}

// ---------------- register-tiled GEMM v2: Y[:, c0:c0+64] = X[N,K] @ W[K,ldw] ----------------
// sX padded to K+4 (conflict-free b128 on both operands); K unrolled by 4.
template<int K, bool BIAS, bool RELU, bool SCALE>
__global__ __launch_bounds__(256) void k_gemm64(const float* __restrict__ X,
                                                const float* __restrict__ W, int ldw,
                                                const float* __restrict__ bias,
                                                const float* __restrict__ rscale,
                                                float* __restrict__ Y, int ldy, int N) {
    constexpr int LDX = K + 4;
    constexpr int KQ = K / 4;
    __shared__ float sX[64 * LDX];
    __shared__ float sW[K * 64];
    const int t = threadIdx.x;
    const int row0 = blockIdx.x * 64;
    const int c0 = blockIdx.y * 64;

    for (int i = t; i < K * 16; i += 256) {
        int k = i >> 4, cq = i & 15;
        *(float4*)&sW[k * 64 + cq * 4] = *(const float4*)&W[(size_t)k * ldw + c0 + cq * 4];
    }
    for (int i = t; i < 64 * KQ; i += 256) {
        int r = i / KQ, kq = i - r * KQ;
        int row = row0 + r;
        float4 xv = (row < N) ? *(const float4*)&X[(size_t)row * K + kq * 4]
                              : make_float4(0.f, 0.f, 0.f, 0.f);
        *(float4*)&sX[r * LDX + kq * 4] = xv;
    }
    __syncthreads();

    const int rg = t >> 4;
    const int cg = t & 15;
    float acc[4][4];
    float binit[4] = {0.f, 0.f, 0.f, 0.f};
    if (BIAS) {
        float4 bv = *(const float4*)&bias[c0 + cg * 4];
        binit[0] = bv.x; binit[1] = bv.y; binit[2] = bv.z; binit[3] = bv.w;
    }
    #pragma unroll
    for (int j = 0; j < 4; ++j)
        #pragma unroll
        for (int c = 0; c < 4; ++c) acc[j][c] = binit[c];

    for (int k0 = 0; k0 < K; k0 += 4) {
        float4 a[4], w[4];
        #pragma unroll
        for (int j = 0; j < 4; ++j) a[j] = *(const float4*)&sX[(rg * 4 + j) * LDX + k0];
        #pragma unroll
        for (int kk = 0; kk < 4; ++kk) w[kk] = *(const float4*)&sW[(k0 + kk) * 64 + cg * 4];
        #pragma unroll
        for (int j = 0; j < 4; ++j) {
            const float* aj = (const float*)&a[j];
            #pragma unroll
            for (int kk = 0; kk < 4; ++kk) {
                float xr = aj[kk];
                acc[j][0] += xr * w[kk].x;
                acc[j][1] += xr * w[kk].y;
                acc[j][2] += xr * w[kk].z;
                acc[j][3] += xr * w[kk].w;
            }
        }
    }

    #pragma unroll
    for (int j = 0; j < 4; ++j) {
        int row = row0 + rg * 4 + j;
        if (row < N) {
            float sc = SCALE ? rscale[row] : 1.0f;
            float4 o;
            o.x = acc[j][0] * sc; o.y = acc[j][1] * sc;
            o.z = acc[j][2] * sc; o.w = acc[j][3] * sc;
            if (RELU) {
                o.x = fmaxf(o.x, 0.f); o.y = fmaxf(o.y, 0.f);
                o.z = fmaxf(o.z, 0.f); o.w = fmaxf(o.w, 0.f);
            }
            *(float4*)&Y[(size_t)row * ldy + c0 + cg * 4] = o;
        }
    }
}

// ---------------- LayerNorm (+ReLU) in place, one wave per row ----------------
template<int C, bool RELU>
__global__ __launch_bounds__(256) void k_ln(float* __restrict__ z, const float* __restrict__ g,
                                            const float* __restrict__ be, int B) {
    int row = blockIdx.x * 4 + (threadIdx.x >> 6);
    int lane = threadIdx.x & 63;
    if (row >= B) return;
    float* zr = z + (size_t)row * C;
    float v0 = zr[lane];
    float v1 = (C == 128) ? zr[lane + 64] : 0.0f;
    float s = v0 + v1, ss = v0 * v0 + v1 * v1;
    #pragma unroll
    for (int m = 32; m; m >>= 1) { s += __shfl_xor(s, m); ss += __shfl_xor(ss, m); }
    float mu = s * (1.0f / C);
    float var = ss * (1.0f / C) - mu * mu;
    float rs = rsqrtf(var + 1e-5f);
    float o0 = (v0 - mu) * rs * g[lane] + be[lane];
    if (RELU) o0 = fmaxf(o0, 0.f);
    zr[lane] = o0;
    if (C == 128) {
        float o1 = (v1 - mu) * rs * g[lane + 64] + be[lane + 64];
        if (RELU) o1 = fmaxf(o1, 0.f);
        zr[lane + 64] = o1;
    }
}

// ---------------- head: dot(z2,w3)+b3 -> sigmoid ----------------
__global__ __launch_bounds__(256) void k_head(const float* __restrict__ z2,
                                              const float* __restrict__ w3,
                                              const float* __restrict__ b3,
                                              float* __restrict__ out, int B) {
    int row = blockIdx.x * 4 + (threadIdx.x >> 6);
    int lane = threadIdx.x & 63;
    if (row >= B) return;
    float p = z2[(size_t)row * 64 + lane] * w3[lane];
    #pragma unroll
    for (int m = 32; m; m >>= 1) p += __shfl_xor(p, m);
    if (lane == 0) out[row] = 1.0f / (1.0f + expf(-(p + b3[0])));
}

extern "C" void kernel_launch(void* const* d_in, const int* in_sizes, int n_in,
                              void* d_out, int out_size, void* d_ws, size_t ws_size,
                              hipStream_t stream) {
    const float* x    = (const float*)d_in[0];
    const int*   src  = (const int*)d_in[1];
    const int*   dst  = (const int*)d_in[2];
    const int*   ui   = (const int*)d_in[3];
    const int*   ii   = (const int*)d_in[4];
    const float* W1   = (const float*)d_in[5];
    const float* b1   = (const float*)d_in[6];
    const float* W2   = (const float*)d_in[7];
    const float* b2   = (const float*)d_in[8];
    const float* fcW1 = (const float*)d_in[9];
    const float* fcb1 = (const float*)d_in[10];
    const float* g1   = (const float*)d_in[11];
    const float* be1  = (const float*)d_in[12];
    const float* fcW2 = (const float*)d_in[13];
    const float* fcb2 = (const float*)d_in[14];
    const float* g2   = (const float*)d_in[15];
    const float* be2  = (const float*)d_in[16];
    const float* fcW3 = (const float*)d_in[17];
    const float* fcb3 = (const float*)d_in[18];
    float* out = (float*)d_out;

    const int N = in_sizes[0] / 64;          // 150000
    const int E = in_sizes[1];               // 2400000
    const int B = in_sizes[3];               // 16384
    const int NBK = (N + BK_NODES - 1) >> BK_SHIFT;   // 293
    const int EB = (E + 2047) / 2048;        // edge blocks

    // ---- workspace layout (126 MB) ----
    float* ws   = (float*)d_ws;
    float* dinv = ws;                                   // N
    int* rowstart = (int*)(dinv + N);                   // N+1
    int* csr      = rowstart + (N + 1);                 // E
    float* bufA = (float*)(csr + E);                    // N*64 : pairBuf+scan scratch, then aggX, then xs2
    float* bufH = bufA + (size_t)N * 64;                // N*128: h1, then cB/z1/z2
    // CSR-build scratch aliased inside bufA (dead before aggX is written)
    int* pairBuf = (int*)bufA;                          // E
    int* chist   = pairBuf + E;                         // 512
    int* bbase   = chist + 512;                         // 513
    int* bcursor = bbase + 513;                         // 512
    // MLP buffers aliased inside bufH (h1 dead after GEMM2)
    float* cB = bufH;                    // B*128
    float* z1 = cB + (size_t)B * 128;    // B*128
    float* z2 = z1 + (size_t)B * 128;    // B*64

    // ---- CSR build ----
    k_zero_i<<<2, 256, 0, stream>>>(chist, 512);
    k_binCount<<<EB, 512, 0, stream>>>(dst, chist, E, NBK);
    k_scanChist<<<1, 512, 0, stream>>>(chist, bbase, bcursor, rowstart, NBK, N, E);
    k_bin<<<EB, 512, 0, stream>>>(src, dst, bcursor, pairBuf, E, NBK);
    k_bscatter<<<NBK, 256, 0, stream>>>(pairBuf, bbase, rowstart, dinv, csr, N);

    // ---- layer 1: h1 = relu((A_hat x) @ W1 + b1) ----
    k_gather64<<<(N + 3) / 4, 256, 0, stream>>>(rowstart, csr, dinv, x, bufA, N);
    k_gemm64<64, true, true, false><<<dim3((N + 63) / 64, 2), 256, 0, stream>>>(
        bufA, W1, 128, b1, nullptr, bufH, 128, N);

    // ---- layer 2: xs2 = dinv * (h1 @ W2); pruned gather + concat -> cB ----
    k_gemm64<128, false, false, true><<<dim3((N + 63) / 64, 1), 256, 0, stream>>>(
        bufH, W2, 64, nullptr, dinv, bufA, 64, N);
    k_gather_pairs<<<B, 128, 0, stream>>>(rowstart, csr, dinv, bufA, b2, ui, ii, cB, B);

    // ---- MLP head ----
    k_gemm64<128, true, false, false><<<dim3(B / 64, 2), 256, 0, stream>>>(
        cB, fcW1, 128, fcb1, nullptr, z1, 128, B);
    k_ln<128, true><<<(B + 3) / 4, 256, 0, stream>>>(z1, g1, be1, B);
    k_gemm64<128, true, false, false><<<dim3(B / 64, 1), 256, 0, stream>>>(
        z1, fcW2, 64, fcb2, nullptr, z2, 64, B);
    k_ln<64, true><<<(B + 3) / 4, 256, 0, stream>>>(z2, g2, be2, B);
    k_head<<<(B + 3) / 4, 256, 0, stream>>>(z2, fcW3, fcb3, out, B);
}

// Round 5
// 502.202 us; speedup vs baseline: 4.3966x; 1.1131x over previous
//
#include <hip/hip_runtime.h>
#include <hip/hip_bf16.h>
#include <math.h>

#define N_USERS_C 100000
#define BK_SHIFT 9
#define BK_NODES 512

// ---------------- small helpers ----------------
__global__ void k_zero_i(int* __restrict__ p, int n) {
    int i = blockIdx.x * 256 + threadIdx.x;
    if (i < n) p[i] = 0;
}

// x (f32) -> packed bf16x2 (RNE)
__global__ void k_tobf16(const float* __restrict__ x, unsigned int* __restrict__ xb, int n2) {
    int i = blockIdx.x * 256 + threadIdx.x;
    if (i >= n2) return;
    float2 v = ((const float2*)x)[i];
    __hip_bfloat16 lo = __float2bfloat16(v.x);
    __hip_bfloat16 hi = __float2bfloat16(v.y);
    unsigned int u = ((unsigned int)(*(unsigned short*)&hi) << 16) | (*(unsigned short*)&lo);
    xb[i] = u;
}

// ---------------- pass 0: coarse histogram over buckets ----------------
__global__ __launch_bounds__(512) void k_binCount(const int* __restrict__ dst,
                                                  int* __restrict__ chist, int E, int nbk) {
    __shared__ int lcnt[BK_NODES];
    int t = threadIdx.x;
    for (int i = t; i < nbk; i += 512) lcnt[i] = 0;
    __syncthreads();
    int e0 = blockIdx.x * 2048;
    #pragma unroll
    for (int j = 0; j < 4; ++j) {
        int e = e0 + j * 512 + t;
        if (e < E) atomicAdd(&lcnt[dst[e] >> BK_SHIFT], 1);
    }
    __syncthreads();
    for (int i = t; i < nbk; i += 512)
        if (lcnt[i]) atomicAdd(&chist[i], lcnt[i]);
}

// ---------------- scan buckets -> bucketBase, cursor; rowstart[N]=E ----------------
__global__ __launch_bounds__(512) void k_scanChist(const int* __restrict__ chist,
                                                   int* __restrict__ base,
                                                   int* __restrict__ cursor,
                                                   int* __restrict__ rowstart,
                                                   int nbk, int N, int E) {
    __shared__ int s[512];
    int t = threadIdx.x;
    int v = (t < nbk) ? chist[t] : 0;
    s[t] = v;
    __syncthreads();
    for (int off = 1; off < 512; off <<= 1) {
        int u = (t >= off) ? s[t - off] : 0;
        __syncthreads();
        s[t] += u;
        __syncthreads();
    }
    int ex = s[t] - v;
    if (t < nbk) { base[t] = ex; cursor[t] = ex; }
    if (t == 0) { base[nbk] = E; rowstart[N] = E; }
}

// ---------------- pass 1: block-local counting sort into bucket regions ----------------
__global__ __launch_bounds__(512) void k_bin(const int* __restrict__ src,
                                             const int* __restrict__ dst,
                                             int* __restrict__ bucketCursor,
                                             int* __restrict__ pairBuf, int E, int nbk) {
    __shared__ int lcnt[BK_NODES];
    __shared__ int scanS[512];
    __shared__ int lofs[BK_NODES];
    __shared__ int delta[BK_NODES];
    __shared__ int sPack[2048];
    __shared__ unsigned short sBkt[2048];
    int t = threadIdx.x;
    int e0 = blockIdx.x * 2048;
    for (int i = t; i < nbk; i += 512) lcnt[i] = 0;
    __syncthreads();

    int mySrc[4], myB[4], myDl[4];
    #pragma unroll
    for (int j = 0; j < 4; ++j) {
        int e = e0 + j * 512 + t;
        if (e < E) {
            int sv = src[e], dv = dst[e];
            mySrc[j] = sv; myB[j] = dv >> BK_SHIFT; myDl[j] = dv & (BK_NODES - 1);
            atomicAdd(&lcnt[myB[j]], 1);
        } else myB[j] = -1;
    }
    __syncthreads();
    int v = (t < nbk) ? lcnt[t] : 0;
    scanS[t] = v;
    __syncthreads();
    for (int off = 1; off < 512; off <<= 1) {
        int u = (t >= off) ? scanS[t - off] : 0;
        __syncthreads();
        scanS[t] += u;
        __syncthreads();
    }
    if (t < nbk) lofs[t] = scanS[t] - v;
    __syncthreads();
    if (t < nbk) {
        int c = lcnt[t];
        int gb = (c > 0) ? atomicAdd(&bucketCursor[t], c) : 0;
        delta[t] = gb - lofs[t];
    }
    __syncthreads();
    #pragma unroll
    for (int j = 0; j < 4; ++j) {
        if (myB[j] >= 0) {
            int p = atomicAdd(&lofs[myB[j]], 1);
            sPack[p] = mySrc[j] | (myDl[j] << 18);   // src < 2^18
            sBkt[p] = (unsigned short)myB[j];
        }
    }
    __syncthreads();
    int total = (E - e0 < 2048) ? (E - e0) : 2048;
    for (int i = t; i < total; i += 512)
        pairBuf[delta[sBkt[i]] + i] = sPack[i];
}

// ---------------- pass 2: per-bucket node hist/scan -> rowstart,dinv; scatter csr ----------------
__global__ __launch_bounds__(256) void k_bscatter(const int* __restrict__ pairBuf,
                                                  const int* __restrict__ base,
                                                  int* __restrict__ rowstart,
                                                  float* __restrict__ dinv,
                                                  int* __restrict__ csr, int N) {
    int b = blockIdx.x;
    int n0 = b << BK_SHIFT;
    int n1 = n0 + BK_NODES; if (n1 > N) n1 = N;
    int nn = n1 - n0;
    __shared__ int hist[BK_NODES];
    __shared__ int curs[BK_NODES];
    __shared__ int ps[256];
    int t = threadIdx.x;
    for (int i = t; i < nn; i += 256) hist[i] = 0;
    __syncthreads();
    int e0 = base[b], e1 = base[b + 1];
    for (int e = e0 + t; e < e1; e += 256)
        atomicAdd(&hist[pairBuf[e] >> 18], 1);
    __syncthreads();
    int h0 = (2 * t < nn) ? hist[2 * t] : 0;
    int h1 = (2 * t + 1 < nn) ? hist[2 * t + 1] : 0;
    int p = h0 + h1;
    ps[t] = p;
    __syncthreads();
    for (int off = 1; off < 256; off <<= 1) {
        int u = (t >= off) ? ps[t - off] : 0;
        __syncthreads();
        ps[t] += u;
        __syncthreads();
    }
    int ex = ps[t] - p;
    if (2 * t < nn) {
        int r0 = e0 + ex;
        rowstart[n0 + 2 * t] = r0; curs[2 * t] = r0;
        dinv[n0 + 2 * t] = rsqrtf((float)(h0 + 1));
    }
    if (2 * t + 1 < nn) {
        int r1 = e0 + ex + h0;
        rowstart[n0 + 2 * t + 1] = r1; curs[2 * t + 1] = r1;
        dinv[n0 + 2 * t + 1] = rsqrtf((float)(h1 + 1));
    }
    __syncthreads();
    for (int e = e0 + t; e < e1; e += 256) {
        int pk = pairBuf[e];
        int pos = atomicAdd(&curs[pk >> 18], 1);
        csr[pos] = pk & 0x3FFFF;
    }
}

// ---------------- gather1: aggX = A_hat x, bf16 rows, 2 edges/iter ----------------
// half h=l>>5 handles edge 2k+h; lane j=l&31 handles features (2j,2j+1) packed in uint.
__global__ __launch_bounds__(256) void k_gather1(const int* __restrict__ rowstart,
                                                 const int* __restrict__ csr,
                                                 const float* __restrict__ dinv,
                                                 const unsigned int* __restrict__ xb,
                                                 const float* __restrict__ x,
                                                 float* __restrict__ out, int N) {
    const int node = blockIdx.x * 4 + (threadIdx.x >> 6);
    const int l = threadIdx.x & 63;
    if (node >= N) return;
    const int h = l >> 5;
    const int j = l & 31;
    const int rs = rowstart[node];
    const int re = rowstart[node + 1];

    float accL = 0.0f, accH = 0.0f;
    for (int base = rs; base < re; base += 64) {
        int idx = base + l;
        int sE = (idx < re) ? csr[idx] : 0;
        float dE = (idx < re) ? dinv[sE] : 0.0f;   // 0 => no contribution
        int cnt = re - base; if (cnt > 64) cnt = 64;
        int iters = (cnt + 1) >> 1;
        for (int k = 0; k < iters; ++k) {
            int e = 2 * k + h;
            int sk = __shfl(sE, e);
            float dk = __shfl(dE, e);
            unsigned int u = xb[(size_t)sk * 32 + j];
            float flo = __uint_as_float(u << 16);
            float fhi = __uint_as_float(u & 0xffff0000u);
            accL += dk * flo;
            accH += dk * fhi;
        }
    }
    accL += __shfl_xor(accL, 32);
    accH += __shfl_xor(accH, 32);
    if (h == 0) {
        float dd = dinv[node];
        float2 xs = ((const float2*)x)[(size_t)node * 32 + j];   // exact f32 self term
        float2 o;
        o.x = dd * accL + dd * dd * xs.x;
        o.y = dd * accH + dd * dd * xs.y;
        ((float2*)out)[(size_t)node * 32 + j] = o;
    }
}

// ---------------- pruned gather2 + concat: cB[b] = [h2(user), h2(item)] ----------------
// xs2 = dinv[row]*(h1@W2) pre-scaled; h2 = dd*(sum_e xs2[src] + xs2[node]) + b2
__global__ __launch_bounds__(128) void k_gather_pairs(const int* __restrict__ rowstart,
                                                      const int* __restrict__ csr,
                                                      const float* __restrict__ dinv,
                                                      const float* __restrict__ xs2,
                                                      const float* __restrict__ b2,
                                                      const int* __restrict__ ui,
                                                      const int* __restrict__ ii,
                                                      float* __restrict__ cB, int B) {
    const int b = blockIdx.x;
    const int wave = threadIdx.x >> 6;   // 0=user, 1=item
    const int l = threadIdx.x & 63;
    const int h = l >> 5;
    const int j = l & 31;
    const int node = (wave == 0) ? (ui[b] - 1) : (N_USERS_C + ii[b] - 1);
    const int rs = rowstart[node];
    const int re = rowstart[node + 1];

    float ax = 0.0f, ay = 0.0f;
    for (int base = rs; base < re; base += 64) {
        int idx = base + l;
        int sE = (idx < re) ? csr[idx] : 0;
        int cnt = re - base; if (cnt > 64) cnt = 64;
        int iters = (cnt + 1) >> 1;
        for (int k = 0; k < iters; ++k) {
            int e = 2 * k + h;
            int sk = __shfl(sE, e);
            float2 v = ((const float2*)xs2)[(size_t)sk * 32 + j];
            if (e < cnt) { ax += v.x; ay += v.y; }
        }
    }
    ax += __shfl_xor(ax, 32);
    ay += __shfl_xor(ay, 32);
    if (h == 0) {
        float dd = dinv[node];
        float2 self = ((const float2*)xs2)[(size_t)node * 32 + j];
        float2 bb = ((const float2*)b2)[j];
        float2 o;
        o.x = dd * (ax + self.x) + bb.x;
        o.y = dd * (ay + self.y) + bb.y;
        ((float2*)cB)[(size_t)b * 64 + wave * 32 + j] = o;
    }
}

// ---------------- register-tiled GEMM: Y[:, c0:c0+64] = X[N,K] @ W[K,ldw] ----------------
template<int K, bool BIAS, bool RELU, bool SCALE>
__global__ __launch_bounds__(256) void k_gemm64(const float* __restrict__ X,
                                                const float* __restrict__ W, int ldw,
                                                const float* __restrict__ bias,
                                                const float* __restrict__ rscale,
                                                float* __restrict__ Y, int ldy, int N) {
    constexpr int LDX = K + 4;
    constexpr int KQ = K / 4;
    __shared__ float sX[64 * LDX];
    __shared__ float sW[K * 64];
    const int t = threadIdx.x;
    const int row0 = blockIdx.x * 64;
    const int c0 = blockIdx.y * 64;

    for (int i = t; i < K * 16; i += 256) {
        int k = i >> 4, cq = i & 15;
        *(float4*)&sW[k * 64 + cq * 4] = *(const float4*)&W[(size_t)k * ldw + c0 + cq * 4];
    }
    for (int i = t; i < 64 * KQ; i += 256) {
        int r = i / KQ, kq = i - r * KQ;
        int row = row0 + r;
        float4 xv = (row < N) ? *(const float4*)&X[(size_t)row * K + kq * 4]
                              : make_float4(0.f, 0.f, 0.f, 0.f);
        *(float4*)&sX[r * LDX + kq * 4] = xv;
    }
    __syncthreads();

    const int rg = t >> 4;
    const int cg = t & 15;
    float acc[4][4];
    float binit[4] = {0.f, 0.f, 0.f, 0.f};
    if (BIAS) {
        float4 bv = *(const float4*)&bias[c0 + cg * 4];
        binit[0] = bv.x; binit[1] = bv.y; binit[2] = bv.z; binit[3] = bv.w;
    }
    #pragma unroll
    for (int j = 0; j < 4; ++j)
        #pragma unroll
        for (int c = 0; c < 4; ++c) acc[j][c] = binit[c];

    for (int k0 = 0; k0 < K; k0 += 4) {
        float4 a[4], w[4];
        #pragma unroll
        for (int j = 0; j < 4; ++j) a[j] = *(const float4*)&sX[(rg * 4 + j) * LDX + k0];
        #pragma unroll
        for (int kk = 0; kk < 4; ++kk) w[kk] = *(const float4*)&sW[(k0 + kk) * 64 + cg * 4];
        #pragma unroll
        for (int j = 0; j < 4; ++j) {
            const float* aj = (const float*)&a[j];
            #pragma unroll
            for (int kk = 0; kk < 4; ++kk) {
                float xr = aj[kk];
                acc[j][0] += xr * w[kk].x;
                acc[j][1] += xr * w[kk].y;
                acc[j][2] += xr * w[kk].z;
                acc[j][3] += xr * w[kk].w;
            }
        }
    }

    #pragma unroll
    for (int j = 0; j < 4; ++j) {
        int row = row0 + rg * 4 + j;
        if (row < N) {
            float sc = SCALE ? rscale[row] : 1.0f;
            float4 o;
            o.x = acc[j][0] * sc; o.y = acc[j][1] * sc;
            o.z = acc[j][2] * sc; o.w = acc[j][3] * sc;
            if (RELU) {
                o.x = fmaxf(o.x, 0.f); o.y = fmaxf(o.y, 0.f);
                o.z = fmaxf(o.z, 0.f); o.w = fmaxf(o.w, 0.f);
            }
            *(float4*)&Y[(size_t)row * ldy + c0 + cg * 4] = o;
        }
    }
}

// ---------------- LayerNorm (+ReLU) in place, one wave per row ----------------
template<int C, bool RELU>
__global__ __launch_bounds__(256) void k_ln(float* __restrict__ z, const float* __restrict__ g,
                                            const float* __restrict__ be, int B) {
    int row = blockIdx.x * 4 + (threadIdx.x >> 6);
    int lane = threadIdx.x & 63;
    if (row >= B) return;
    float* zr = z + (size_t)row * C;
    float v0 = zr[lane];
    float v1 = (C == 128) ? zr[lane + 64] : 0.0f;
    float s = v0 + v1, ss = v0 * v0 + v1 * v1;
    #pragma unroll
    for (int m = 32; m; m >>= 1) { s += __shfl_xor(s, m); ss += __shfl_xor(ss, m); }
    float mu = s * (1.0f / C);
    float var = ss * (1.0f / C) - mu * mu;
    float rs = rsqrtf(var + 1e-5f);
    float o0 = (v0 - mu) * rs * g[lane] + be[lane];
    if (RELU) o0 = fmaxf(o0, 0.f);
    zr[lane] = o0;
    if (C == 128) {
        float o1 = (v1 - mu) * rs * g[lane + 64] + be[lane + 64];
        if (RELU) o1 = fmaxf(o1, 0.f);
        zr[lane + 64] = o1;
    }
}

// ---------------- head: dot(z2,w3)+b3 -> sigmoid ----------------
__global__ __launch_bounds__(256) void k_head(const float* __restrict__ z2,
                                              const float* __restrict__ w3,
                                              const float* __restrict__ b3,
                                              float* __restrict__ out, int B) {
    int row = blockIdx.x * 4 + (threadIdx.x >> 6);
    int lane = threadIdx.x & 63;
    if (row >= B) return;
    float p = z2[(size_t)row * 64 + lane] * w3[lane];
    #pragma unroll
    for (int m = 32; m; m >>= 1) p += __shfl_xor(p, m);
    if (lane == 0) out[row] = 1.0f / (1.0f + expf(-(p + b3[0])));
}

extern "C" void kernel_launch(void* const* d_in, const int* in_sizes, int n_in,
                              void* d_out, int out_size, void* d_ws, size_t ws_size,
                              hipStream_t stream) {
    const float* x    = (const float*)d_in[0];
    const int*   src  = (const int*)d_in[1];
    const int*   dst  = (const int*)d_in[2];
    const int*   ui   = (const int*)d_in[3];
    const int*   ii   = (const int*)d_in[4];
    const float* W1   = (const float*)d_in[5];
    const float* b1   = (const float*)d_in[6];
    const float* W2   = (const float*)d_in[7];
    const float* b2   = (const float*)d_in[8];
    const float* fcW1 = (const float*)d_in[9];
    const float* fcb1 = (const float*)d_in[10];
    const float* g1   = (const float*)d_in[11];
    const float* be1  = (const float*)d_in[12];
    const float* fcW2 = (const float*)d_in[13];
    const float* fcb2 = (const float*)d_in[14];
    const float* g2   = (const float*)d_in[15];
    const float* be2  = (const float*)d_in[16];
    const float* fcW3 = (const float*)d_in[17];
    const float* fcb3 = (const float*)d_in[18];
    float* out = (float*)d_out;

    const int N = in_sizes[0] / 64;          // 150000
    const int E = in_sizes[1];               // 2400000
    const int B = in_sizes[3];               // 16384
    const int NBK = (N + BK_NODES - 1) >> BK_SHIFT;   // 293
    const int EB = (E + 2047) / 2048;        // edge blocks

    // ---- workspace layout (126 MB) ----
    float* ws   = (float*)d_ws;
    float* dinv = ws;                                   // N
    int* rowstart = (int*)(dinv + N);                   // N+1
    int* csr      = rowstart + (N + 1);                 // E
    float* bufA = (float*)(csr + E);                    // N*64 : pairBuf scratch, then aggX, then xs2
    float* bufH = bufA + (size_t)N * 64;                // N*128: xb, then h1, then cB/z1/z2
    // CSR-build scratch aliased inside bufA (dead before aggX is written)
    int* pairBuf = (int*)bufA;                          // E
    int* chist   = pairBuf + E;                         // 512
    int* bbase   = chist + 512;                         // 513
    int* bcursor = bbase + 513;                         // 512
    // bf16 x aliased at start of bufH (dead once gemm1 writes h1)
    unsigned int* xb = (unsigned int*)bufH;             // N*32 uints = 19.2 MB
    // MLP buffers aliased inside bufH (h1 dead after GEMM2)
    float* cB = bufH;                    // B*128
    float* z1 = cB + (size_t)B * 128;    // B*128
    float* z2 = z1 + (size_t)B * 128;    // B*64

    // ---- bf16 copy of x ----
    k_tobf16<<<(N * 32 + 255) / 256, 256, 0, stream>>>(x, xb, N * 32);

    // ---- CSR build ----
    k_zero_i<<<2, 256, 0, stream>>>(chist, 512);
    k_binCount<<<EB, 512, 0, stream>>>(dst, chist, E, NBK);
    k_scanChist<<<1, 512, 0, stream>>>(chist, bbase, bcursor, rowstart, NBK, N, E);
    k_bin<<<EB, 512, 0, stream>>>(src, dst, bcursor, pairBuf, E, NBK);
    k_bscatter<<<NBK, 256, 0, stream>>>(pairBuf, bbase, rowstart, dinv, csr, N);

    // ---- layer 1: h1 = relu((A_hat x) @ W1 + b1) ----
    k_gather1<<<(N + 3) / 4, 256, 0, stream>>>(rowstart, csr, dinv, xb, x, bufA, N);
    k_gemm64<64, true, true, false><<<dim3((N + 63) / 64, 2), 256, 0, stream>>>(
        bufA, W1, 128, b1, nullptr, bufH, 128, N);

    // ---- layer 2: xs2 = dinv * (h1 @ W2); pruned gather + concat -> cB ----
    k_gemm64<128, false, false, true><<<dim3((N + 63) / 64, 1), 256, 0, stream>>>(
        bufH, W2, 64, nullptr, dinv, bufA, 64, N);
    k_gather_pairs<<<B, 128, 0, stream>>>(rowstart, csr, dinv, bufA, b2, ui, ii, cB, B);

    // ---- MLP head ----
    k_gemm64<128, true, false, false><<<dim3(B / 64, 2), 256, 0, stream>>>(
        cB, fcW1, 128, fcb1, nullptr, z1, 128, B);
    k_ln<128, true><<<(B + 3) / 4, 256, 0, stream>>>(z1, g1, be1, B);
    k_gemm64<128, true, false, false><<<dim3(B / 64, 1), 256, 0, stream>>>(
        z1, fcW2, 64, fcb2, nullptr, z2, 64, B);
    k_ln<64, true><<<(B + 3) / 4, 256, 0, stream>>>(z2, g2, be2, B);
    k_head<<<(B + 3) / 4, 256, 0, stream>>>(z2, fcW3, fcb3, out, B);
}